// Round 1
// baseline (924.504 us; speedup 1.0000x reference)
//
#include <hip/hip_runtime.h>
#include <math.h>

#define NN 100000
#define EE 1600000
#define GG 64
#define HH 64
#define LHH 128
#define AA 10

// ---------------- helpers ----------------
__device__ __forceinline__ float wave_sum(float v) {
#pragma unroll
    for (int m = 32; m >= 1; m >>= 1) v += __shfl_xor(v, m, 64);
    return v;
}
__device__ __forceinline__ float wave_max(float v) {
#pragma unroll
    for (int m = 32; m >= 1; m >>= 1) v = fmaxf(v, __shfl_xor(v, m, 64));
    return v;
}
__device__ __forceinline__ float sigmoidf(float x) { return 1.f / (1.f + expf(-x)); }

// ---------------- encoder: h = LN(relu(x@enc_w + enc_b)) ----------------
__global__ __launch_bounds__(256) void enc_kernel(
    const float* __restrict__ x, const float* __restrict__ enc_w,
    const float* __restrict__ enc_b, const float* __restrict__ ln_g,
    const float* __restrict__ ln_b, float* __restrict__ h) {
    __shared__ float sw[5 * 64];
    int t = threadIdx.x;
    for (int i = t; i < 5 * 64; i += 256) sw[i] = enc_w[i];
    __syncthreads();
    int wave = t >> 6, lane = t & 63;
    int v = blockIdx.x * 4 + wave;
    if (v >= NN) return;
    float a = enc_b[lane];
#pragma unroll
    for (int k = 0; k < 5; ++k) a += x[v * 5 + k] * sw[k * 64 + lane];
    a = fmaxf(a, 0.f);
    float mu = wave_sum(a) * (1.f / 64.f);
    float d = a - mu;
    float var = wave_sum(d * d) * (1.f / 64.f);
    float r = 1.f / sqrtf(var + 1e-5f);
    h[(size_t)v * 64 + lane] = d * r * ln_g[lane] + ln_b[lane];
}

// ---------------- in-place hw = h@W ; as_n = hw@a_s ; ad_n = hw@a_d ----------------
__global__ __launch_bounds__(256) void mm_kernel(
    float* __restrict__ buf, const float* __restrict__ W,
    const float* __restrict__ avs, const float* __restrict__ avd,
    float* __restrict__ as_out, float* __restrict__ ad_out) {
    __shared__ float sW[64 * 64];
    __shared__ float srow[4][64];
    int t = threadIdx.x;
    for (int i = t; i < 64 * 64; i += 256) sW[i] = W[i];
    int wave = t >> 6, lane = t & 63;
    int v = blockIdx.x * 4 + wave;
    __syncthreads();
    if (v < NN) srow[wave][lane] = buf[(size_t)v * 64 + lane];
    __syncthreads();
    if (v >= NN) return;
    float acc = 0.f;
#pragma unroll
    for (int k = 0; k < 64; ++k) acc += srow[wave][k] * sW[k * 64 + lane];
    float pa = wave_sum(acc * avs[lane]);
    float pd = wave_sum(acc * avd[lane]);
    if (lane == 0) { as_out[v] = pa; ad_out[v] = pd; }
    buf[(size_t)v * 64 + lane] = acc;
}

// ---------------- CSR build ----------------
__global__ __launch_bounds__(256) void hist_kernel(const int* __restrict__ dst,
                                                   int* __restrict__ cnt) {
    int i = blockIdx.x * 256 + threadIdx.x;
    if (i < EE) atomicAdd(&cnt[dst[i]], 1);
}

__global__ __launch_bounds__(256) void scan1_kernel(const int* __restrict__ cnt,
                                                    int* __restrict__ row_off,
                                                    int* __restrict__ bsum) {
    __shared__ int sd[256];
    int t = threadIdx.x, b = blockIdx.x;
    int base = b * 1024 + t * 4;
    int v0 = (base + 0 < NN) ? cnt[base + 0] : 0;
    int v1 = (base + 1 < NN) ? cnt[base + 1] : 0;
    int v2 = (base + 2 < NN) ? cnt[base + 2] : 0;
    int v3 = (base + 3 < NN) ? cnt[base + 3] : 0;
    int tot = v0 + v1 + v2 + v3;
    sd[t] = tot;
    __syncthreads();
    for (int off = 1; off < 256; off <<= 1) {
        int xx = (t >= off) ? sd[t - off] : 0;
        __syncthreads();
        sd[t] += xx;
        __syncthreads();
    }
    int excl = sd[t] - tot;
    if (t == 255) bsum[b] = sd[255];
    int p = excl;
    if (base + 0 < NN) row_off[base + 0] = p; p += v0;
    if (base + 1 < NN) row_off[base + 1] = p; p += v1;
    if (base + 2 < NN) row_off[base + 2] = p; p += v2;
    if (base + 3 < NN) row_off[base + 3] = p;
}

__global__ __launch_bounds__(128) void scan2_kernel(int* __restrict__ bsum, int nb) {
    __shared__ int sd[128];
    int t = threadIdx.x;
    int v = (t < nb) ? bsum[t] : 0;
    sd[t] = v;
    __syncthreads();
    for (int off = 1; off < 128; off <<= 1) {
        int xx = (t >= off) ? sd[t - off] : 0;
        __syncthreads();
        sd[t] += xx;
        __syncthreads();
    }
    if (t < nb) bsum[t] = sd[t] - v;  // exclusive
}

__global__ __launch_bounds__(256) void scan3_kernel(int* __restrict__ row_off,
                                                    const int* __restrict__ bsum,
                                                    int* __restrict__ cursor) {
    int idx = blockIdx.x * 256 + threadIdx.x;
    if (idx < NN) {
        int r = row_off[idx] + bsum[idx >> 10];
        row_off[idx] = r;
        cursor[idx] = r;
    }
    if (idx == 0) row_off[NN] = EE;
}

__global__ __launch_bounds__(256) void scatter_kernel(const int* __restrict__ src,
                                                      const int* __restrict__ dst,
                                                      int* __restrict__ cursor,
                                                      int* __restrict__ csr_src) {
    int i = blockIdx.x * 256 + threadIdx.x;
    if (i >= EE) return;
    int d = dst[i];
    int pos = atomicAdd(&cursor[d], 1);
    csr_src[pos] = src[i];
}

// ---------------- GAT: wave per dst node, online softmax, register accumulate ----------------
__global__ __launch_bounds__(256) void gat_kernel(
    const float* __restrict__ X,  // hw [N,64]
    const float* __restrict__ asn, const float* __restrict__ adn,
    const int* __restrict__ row_off, const int* __restrict__ csr_src,
    const float* __restrict__ bias, float* __restrict__ Y) {
    int t = threadIdx.x;
    int wave = t >> 6, lane = t & 63;
    int v = blockIdx.x * 4 + wave;
    if (v >= NN) return;
    float adv = adn[v];
    // self loop: e_self = leaky(asn[v] + adv)
    float es = asn[v] + adv;
    es = (es >= 0.f) ? es : 0.2f * es;
    float m = es;
    float den = 1.f;                             // exp(es - m) = 1
    float acc = X[(size_t)v * 64 + lane];        // 1 * hw[v]
    int beg = row_off[v], end = row_off[v + 1];
    int sN = (beg < end) ? csr_src[beg] : 0;
    float aN = (beg < end) ? asn[sN] : 0.f;
    for (int i = beg; i < end; ++i) {
        int s = sN;
        float asv = aN;
        float xv = X[(size_t)s * 64 + lane];
        if (i + 1 < end) {  // prefetch next edge's scalars
            sN = csr_src[i + 1];
            aN = asn[sN];
        }
        float e = asv + adv;
        e = (e >= 0.f) ? e : 0.2f * e;
        float mn = fmaxf(m, e);
        float sc = expf(m - mn);
        float ex = expf(e - mn);
        den = den * sc + ex;
        acc = acc * sc + ex * xv;
        m = mn;
    }
    float o = acc / (den + 1e-16f) + bias[lane];
    Y[(size_t)v * 64 + lane] = fmaxf(o, 0.f);
}

// ---------------- global attention pool ----------------
__device__ __forceinline__ int lbound(const int* a, int n, int key) {
    int lo = 0, hi = n;
    while (lo < hi) {
        int mid = (lo + hi) >> 1;
        if (a[mid] < key) lo = mid + 1; else hi = mid;
    }
    return lo;
}

__global__ __launch_bounds__(256) void pool_kernel(
    const float* __restrict__ Hf, const int* __restrict__ batch,
    const float* __restrict__ gate_w, const float* __restrict__ gate_b,
    float* __restrict__ gatebuf, float* __restrict__ pooled) {
    int g = blockIdx.x;
    __shared__ int sRange[2];
    if (threadIdx.x == 0) sRange[0] = lbound(batch, NN, g);
    if (threadIdx.x == 1) sRange[1] = lbound(batch, NN, g + 1);
    __syncthreads();
    int beg = sRange[0], end = sRange[1];
    int wave = threadIdx.x >> 6, lane = threadIdx.x & 63;
    float gw = gate_w[lane];
    float gb = gate_b[0];
    float mloc = -INFINITY;
    for (int v = beg + wave; v < end; v += 4) {
        float gate = wave_sum(Hf[(size_t)v * 64 + lane] * gw) + gb;
        if (lane == 0) gatebuf[v] = gate;
        mloc = fmaxf(mloc, gate);
    }
    __shared__ float smax[4];
    if (lane == 0) smax[wave] = mloc;
    __syncthreads();
    float m = fmaxf(fmaxf(smax[0], smax[1]), fmaxf(smax[2], smax[3]));
    float den = 0.f, acc = 0.f;
    for (int v = beg + wave; v < end; v += 4) {
        float ex = expf(gatebuf[v] - m);
        den += ex;
        acc += ex * Hf[(size_t)v * 64 + lane];
    }
    __shared__ float sacc[4][64];
    __shared__ float sden[4];
    sacc[wave][lane] = acc;
    if (lane == 0) sden[wave] = den;
    __syncthreads();
    if (wave == 0) {
        float a = sacc[0][lane] + sacc[1][lane] + sacc[2][lane] + sacc[3][lane];
        float d = sden[0] + sden[1] + sden[2] + sden[3];
        pooled[g * 64 + lane] = a / (d + 1e-16f);
    }
}

// ---------------- LSTM (h0=c0=0) + MLP head ----------------
__global__ __launch_bounds__(256) void head_kernel(
    const float* __restrict__ pooled, const float* __restrict__ w_ih,
    const float* __restrict__ b_ih, const float* __restrict__ b_hh,
    const float* __restrict__ q_w1, const float* __restrict__ q_b1,
    const float* __restrict__ q_w2, const float* __restrict__ q_b2,
    float* __restrict__ out) {
    int g = blockIdx.x, t = threadIdx.x;
    __shared__ float sp[64];
    __shared__ float sg[512];
    __shared__ float sh1[128];
    __shared__ float ss1[64];
    if (t < 64) sp[t] = pooled[g * 64 + t];
    __syncthreads();
    for (int r = t; r < 512; r += 256) {
        const float* wr = w_ih + (size_t)r * 64;
        float a = b_ih[r] + b_hh[r];
#pragma unroll
        for (int k = 0; k < 64; ++k) a += sp[k] * wr[k];
        sg[r] = a;
    }
    __syncthreads();
    if (t < 128) {
        float ig = sg[t], gg = sg[256 + t], og = sg[384 + t];
        float c1 = sigmoidf(ig) * tanhf(gg);  // sigmoid(f)*c0 == 0
        float h1 = sigmoidf(og) * tanhf(c1);
        sh1[t] = h1;
        out[640 + g * 128 + t] = h1;
        out[640 + 8192 + g * 128 + t] = c1;
    }
    __syncthreads();
    if (t < 64) {
        float a = q_b1[t];
#pragma unroll
        for (int k = 0; k < 128; ++k) a += sh1[k] * q_w1[k * 64 + t];
        ss1[t] = fmaxf(a, 0.f);
    }
    __syncthreads();
    if (t < 10) {
        float a = q_b2[t];
#pragma unroll
        for (int k = 0; k < 64; ++k) a += ss1[k] * q_w2[k * 10 + t];
        out[g * 10 + t] = a;
    }
}

// ---------------- launcher ----------------
extern "C" void kernel_launch(void* const* d_in, const int* in_sizes, int n_in,
                              void* d_out, int out_size, void* d_ws, size_t ws_size,
                              hipStream_t stream) {
    const float* x = (const float*)d_in[0];
    const int* edge_index = (const int*)d_in[1];
    const int* batch = (const int*)d_in[2];
    const float* enc_w = (const float*)d_in[3];
    const float* enc_b = (const float*)d_in[4];
    const float* ln_g = (const float*)d_in[5];
    const float* ln_b = (const float*)d_in[6];
    const float* w1 = (const float*)d_in[7];
    const float* a1s = (const float*)d_in[8];
    const float* a1d = (const float*)d_in[9];
    const float* b1 = (const float*)d_in[10];
    const float* w2 = (const float*)d_in[11];
    const float* a2s = (const float*)d_in[12];
    const float* a2d = (const float*)d_in[13];
    const float* b2 = (const float*)d_in[14];
    const float* gate_w = (const float*)d_in[15];
    const float* gate_b = (const float*)d_in[16];
    const float* w_ih = (const float*)d_in[17];
    // d_in[18] = w_hh unused (h0 = 0)
    const float* b_ih = (const float*)d_in[19];
    const float* b_hh = (const float*)d_in[20];
    const float* q_w1 = (const float*)d_in[21];
    const float* q_b1 = (const float*)d_in[22];
    const float* q_w2 = (const float*)d_in[23];
    const float* q_b2 = (const float*)d_in[24];
    float* out = (float*)d_out;

    const int* e_src = edge_index;
    const int* e_dst = edge_index + EE;

    // workspace carve-up
    char* ws = (char*)d_ws;
    size_t off = 0;
    auto alloc = [&](size_t bytes) {
        size_t r = off;
        off = (off + bytes + 255) & ~(size_t)255;
        return r;
    };
    float* bufA = (float*)(ws + alloc((size_t)NN * 64 * 4));
    float* bufB = (float*)(ws + alloc((size_t)NN * 64 * 4));
    float* as_n = (float*)(ws + alloc((size_t)NN * 4));  // reused as gatebuf
    float* ad_n = (float*)(ws + alloc((size_t)NN * 4));
    int* cntcur = (int*)(ws + alloc((size_t)NN * 4));
    int* row_off = (int*)(ws + alloc((size_t)(NN + 1) * 4));
    int* csr_src = (int*)(ws + alloc((size_t)EE * 4));
    int* bsum = (int*)(ws + alloc(128 * 4));
    float* pooled = (float*)(ws + alloc((size_t)GG * 64 * 4));
    (void)ws_size;

    const int nodeBlocks = (NN + 3) / 4;        // wave per node
    const int edgeBlocks = (EE + 255) / 256;
    const int scan1Blocks = (NN + 1023) / 1024; // 98
    const int scan3Blocks = (NN + 255) / 256;

    // encoder
    enc_kernel<<<nodeBlocks, 256, 0, stream>>>(x, enc_w, enc_b, ln_g, ln_b, bufA);

    // CSR by dst (reused by both GAT layers)
    hipMemsetAsync(cntcur, 0, (size_t)NN * 4, stream);
    hist_kernel<<<edgeBlocks, 256, 0, stream>>>(e_dst, cntcur);
    scan1_kernel<<<scan1Blocks, 256, 0, stream>>>(cntcur, row_off, bsum);
    scan2_kernel<<<1, 128, 0, stream>>>(bsum, scan1Blocks);
    scan3_kernel<<<scan3Blocks, 256, 0, stream>>>(row_off, bsum, cntcur);
    scatter_kernel<<<edgeBlocks, 256, 0, stream>>>(e_src, e_dst, cntcur, csr_src);

    // GAT layer 1: bufA(h) -> in-place hw -> bufB(h1)
    mm_kernel<<<nodeBlocks, 256, 0, stream>>>(bufA, w1, a1s, a1d, as_n, ad_n);
    gat_kernel<<<nodeBlocks, 256, 0, stream>>>(bufA, as_n, ad_n, row_off, csr_src, b1, bufB);

    // GAT layer 2: bufB -> in-place hw -> bufA(h2)
    mm_kernel<<<nodeBlocks, 256, 0, stream>>>(bufB, w2, a2s, a2d, as_n, ad_n);
    gat_kernel<<<nodeBlocks, 256, 0, stream>>>(bufB, as_n, ad_n, row_off, csr_src, b2, bufA);

    // global attention pool (as_n reused as gate scratch)
    pool_kernel<<<GG, 256, 0, stream>>>(bufA, batch, gate_w, gate_b, as_n, pooled);

    // LSTM + MLP head
    head_kernel<<<GG, 256, 0, stream>>>(pooled, w_ih, b_ih, b_hh, q_w1, q_b1, q_w2, q_b2, out);
}